// Round 3
// baseline (438.938 us; speedup 1.0000x reference)
//
#include <hip/hip_runtime.h>
#include <hip/hip_fp16.h>

#define NN 50000
#define EE 800000
#define ET (EE + NN)      // edges + self loops = 850000
#define IND 128
#define F1 256            // HEADS*HID
#define H1 8
#define D1 32
#define F2 64
#define NEG 0.2f
#define EPSV 1e-16f

// ---------------- CSR build ----------------
__global__ void k_hist(const int* __restrict__ ei, int* __restrict__ deg) {
  int e = blockIdx.x * blockDim.x + threadIdx.x;
  if (e >= ET) return;
  int d = (e < EE) ? ei[EE + e] : (e - EE);
  atomicAdd(&deg[d], 1);
}

__global__ void k_scan1(const int* __restrict__ deg, int* __restrict__ incl,
                        int* __restrict__ blks) {
  __shared__ int sm[256];
  int t = threadIdx.x;
  int i = blockIdx.x * 256 + t;
  int v = (i < NN) ? deg[i] : 0;
  sm[t] = v;
  __syncthreads();
  for (int off = 1; off < 256; off <<= 1) {
    int add = (t >= off) ? sm[t - off] : 0;
    __syncthreads();
    sm[t] += add;
    __syncthreads();
  }
  if (i < NN) incl[i] = sm[t];
  if (t == 255) blks[blockIdx.x] = sm[t];
}

__global__ void k_scan2(int* __restrict__ blks, int nb) {
  __shared__ int sm[256];
  int t = threadIdx.x;
  sm[t] = (t < nb) ? blks[t] : 0;
  __syncthreads();
  for (int off = 1; off < 256; off <<= 1) {
    int add = (t >= off) ? sm[t - off] : 0;
    __syncthreads();
    sm[t] += add;
    __syncthreads();
  }
  if (t < nb) blks[t] = sm[t];
}

__global__ void k_scan3(const int* __restrict__ deg, const int* __restrict__ blks,
                        int* __restrict__ rowp, int* __restrict__ cursor) {
  int b = blockIdx.x;
  int i = b * 256 + threadIdx.x;
  if (i == 0) rowp[NN] = ET;
  if (i >= NN) return;
  int base = (b > 0) ? blks[b - 1] : 0;
  int excl = rowp[i] - deg[i] + base;
  rowp[i] = excl;
  cursor[i] = excl;
}

__global__ void k_scatter(const int* __restrict__ ei, int* __restrict__ cursor,
                          int* __restrict__ csr) {
  int e = blockIdx.x * blockDim.x + threadIdx.x;
  if (e >= ET) return;
  int s, d;
  if (e < EE) { s = ei[e]; d = ei[EE + e]; }
  else        { s = e - EE; d = s; }
  int pos = atomicAdd(&cursor[d], 1);
  csr[pos] = s;
}

// ---------------- GEMM: C[M,Nc] = A[M,K] * B[Nc,K]^T ----------------
// 64x64 tile, 256 threads, 4x4 per thread. Also emits an fp16 copy of C in
// head-major-32 layout: Ch[(c>>5)*M*32 + m*32 + (c&31)].
template<int BK>
__global__ void k_gemm_nt(const float* __restrict__ A, const float* __restrict__ B,
                          float* __restrict__ C, __half* __restrict__ Ch,
                          int M, int Nc, int K) {
  __shared__ float As[BK][64];
  __shared__ float Bs[BK][64];
  int tid = threadIdx.x;
  int tx = tid & 15, ty = tid >> 4;
  int m0 = blockIdx.x * 64, n0 = blockIdx.y * 64;
  int lrow = tid >> 2;          // 0..63
  int lk = (tid & 3) * 4;       // 0,4,8,12
  float acc[4][4] = {};
  for (int k0 = 0; k0 < K; k0 += BK) {
    {
      int m = m0 + lrow;
      float4 av = make_float4(0.f, 0.f, 0.f, 0.f);
      if (m < M) av = *(const float4*)(A + (size_t)m * K + k0 + lk);
      As[lk + 0][lrow] = av.x; As[lk + 1][lrow] = av.y;
      As[lk + 2][lrow] = av.z; As[lk + 3][lrow] = av.w;
      int c = n0 + lrow;        // Nc is a multiple of 64: always valid
      float4 bv = *(const float4*)(B + (size_t)c * K + k0 + lk);
      Bs[lk + 0][lrow] = bv.x; Bs[lk + 1][lrow] = bv.y;
      Bs[lk + 2][lrow] = bv.z; Bs[lk + 3][lrow] = bv.w;
    }
    __syncthreads();
#pragma unroll
    for (int kk = 0; kk < BK; ++kk) {
      float4 a4 = *(const float4*)&As[kk][ty * 4];
      float4 b4 = *(const float4*)&Bs[kk][tx * 4];
      float ar[4] = {a4.x, a4.y, a4.z, a4.w};
      float br[4] = {b4.x, b4.y, b4.z, b4.w};
#pragma unroll
      for (int i = 0; i < 4; ++i)
#pragma unroll
        for (int j = 0; j < 4; ++j)
          acc[i][j] += ar[i] * br[j];
    }
    __syncthreads();
  }
  int c0 = n0 + tx * 4;
#pragma unroll
  for (int i = 0; i < 4; ++i) {
    int m = m0 + ty * 4 + i;
    if (m < M) {
      float4 o = make_float4(acc[i][0], acc[i][1], acc[i][2], acc[i][3]);
      *(float4*)(C + (size_t)m * Nc + c0) = o;
      __half2 p0 = __floats2half2_rn(acc[i][0], acc[i][1]);
      __half2 p1 = __floats2half2_rn(acc[i][2], acc[i][3]);
      float2 packed;
      *(__half2*)&packed.x = p0;
      *(__half2*)&packed.y = p1;
      // head-major: slice = c0>>5, elem = c0&31 (4 consecutive, same slice)
      *(float2*)(Ch + ((size_t)(c0 >> 5) * M + m) * 32 + (c0 & 31)) = packed;
    }
  }
}

// ---------------- per-node attention logits (transposed out [H][N]) -------
template<int H, int D>
__global__ void k_att(const float* __restrict__ h, const float* __restrict__ atts,
                      const float* __restrict__ attd, float* __restrict__ as_t,
                      float* __restrict__ ad_t) {
  int idx = blockIdx.x * blockDim.x + threadIdx.x;
  if (idx >= NN * H) return;
  int hh = idx / NN, n = idx % NN;
  const float* hp = h + (size_t)n * (H * D) + hh * D;
  const float* sp = atts + hh * D;
  const float* dp = attd + hh * D;
  float s_ = 0.f, d_ = 0.f;
#pragma unroll
  for (int j = 0; j < D; j += 4) {
    float4 hv = *(const float4*)(hp + j);
    float4 sv = *(const float4*)(sp + j);
    float4 dv = *(const float4*)(dp + j);
    s_ += hv.x * sv.x + hv.y * sv.y + hv.z * sv.z + hv.w * sv.w;
    d_ += hv.x * dv.x + hv.y * dv.y + hv.z * dv.z + hv.w * dv.w;
  }
  as_t[idx] = s_;   // idx == hh*NN + n
  ad_t[idx] = d_;
}

// ---------------- aggregation: slice-split, XCD-pinned ----------------
// Feature matrix is [NSPLIT][NN][32] fp16. Slice = blockIdx.x % NSPLIT so the
// round-robin block->XCD dispatch pins each slice's 3.2MB working set to one
// XCD's L2. One wave per (dest node, slice); 4 edges/iter, 16 lanes/edge
// (half2 each). Softmax normalization folded into the final divide.
template<int NSPLIT, int HATT, int F, int BPS, bool RELU>
__global__ void k_aggs(const int* __restrict__ rowp, const int* __restrict__ csr,
                       const __half* __restrict__ feat, const float* __restrict__ as_t,
                       const float* __restrict__ ad_t, const float* __restrict__ bias,
                       float* __restrict__ out) {
  const int split = blockIdx.x % NSPLIT;
  const int chunk = blockIdx.x / NSPLIT;
  const int lane = threadIdx.x & 63;
  const int sub = lane >> 4;        // edge slot 0..3
  const int ep = lane & 15;         // element pair 0..15
  const int att = (HATT == 1) ? 0 : split;
  const int wave0 = chunk * 4 + (threadIdx.x >> 6);
  const __half* fbase = feat + (size_t)split * NN * 32 + ep * 2;
  const float* asb = as_t + (size_t)att * NN;
  const float* adb = ad_t + (size_t)att * NN;
  const float b0 = bias[split * 32 + ep * 2];
  const float b1 = bias[split * 32 + ep * 2 + 1];
  for (int d = wave0; d < NN; d += BPS * 4) {
    int p0 = rowp[d], p1 = rowp[d + 1];
    float adv = adb[d];
    float a0 = 0.f, a1 = 0.f, ws = 0.f;
#pragma unroll 2
    for (int base = p0; base < p1; base += 4) {
      int p = base + sub;
      bool v = p < p1;
      int s = csr[v ? p : base];
      float a = asb[s] + adv;
      a = (a > 0.f) ? a : NEG * a;
      float wgt = v ? __expf(a) : 0.f;
      ws += wgt;
      float2 f2 = __half22float2(*(const __half2*)(fbase + (size_t)s * 32));
      a0 += wgt * f2.x;
      a1 += wgt * f2.y;
    }
    a0 += __shfl_xor(a0, 16); a0 += __shfl_xor(a0, 32);
    a1 += __shfl_xor(a1, 16); a1 += __shfl_xor(a1, 32);
    ws += __shfl_xor(ws, 16); ws += __shfl_xor(ws, 32);
    if (sub == 0) {
      float inv = 1.f / (ws + EPSV);
      float2 o;
      o.x = a0 * inv + b0;
      o.y = a1 * inv + b1;
      if (RELU) { o.x = fmaxf(o.x, 0.f); o.y = fmaxf(o.y, 0.f); }
      *(float2*)(out + (size_t)d * F + split * 32 + ep * 2) = o;
    }
  }
}

extern "C" void kernel_launch(void* const* d_in, const int* in_sizes, int n_in,
                              void* d_out, int out_size, void* d_ws, size_t ws_size,
                              hipStream_t stream) {
  const float* x    = (const float*)d_in[0];
  const int*   ei   = (const int*)d_in[1];
  const float* W1   = (const float*)d_in[2];
  const float* as1w = (const float*)d_in[3];
  const float* ad1w = (const float*)d_in[4];
  const float* b1   = (const float*)d_in[5];
  const float* W2   = (const float*)d_in[6];
  const float* as2w = (const float*)d_in[7];
  const float* ad2w = (const float*)d_in[8];
  const float* b2   = (const float*)d_in[9];
  float* out = (float*)d_out;

  float* ws  = (float*)d_ws;
  float* h1  = ws;                          // N*256 fp32
  float* h2  = h1 + (size_t)NN * F1;        // N*256 fp32
  float* as1 = h2 + (size_t)NN * F1;        // [H1][N]
  float* ad1 = as1 + (size_t)NN * H1;       // [H1][N]
  float* as2 = ad1 + (size_t)NN * H1;       // N
  float* ad2 = as2 + NN;                    // N
  int* deg    = (int*)(ad2 + NN);           // N
  int* rowp   = deg + NN;                   // N+1
  int* cursor = rowp + NN + 1;              // N
  int* blks   = cursor + NN;                // 256
  int* csr    = blks + 256;                 // ET
  __half* h1h = (__half*)(csr + ET);        // [8][N][32] fp16
  __half* hmh = h1h;                        // reuse: [2][N][32] fp16
  float* hm   = h1;                         // reuse h1 for layer-2 messages [N,64]

  hipMemsetAsync(deg, 0, NN * sizeof(int), stream);
  int nbE = (ET + 255) / 256;
  int nbN = (NN + 255) / 256;               // 196
  k_hist<<<nbE, 256, 0, stream>>>(ei, deg);
  k_scan1<<<nbN, 256, 0, stream>>>(deg, rowp, blks);
  k_scan2<<<1, 256, 0, stream>>>(blks, nbN);
  k_scan3<<<nbN, 256, 0, stream>>>(deg, blks, rowp, cursor);
  k_scatter<<<nbE, 256, 0, stream>>>(ei, cursor, csr);

  // layer 1
  k_gemm_nt<16><<<dim3((NN + 63) / 64, F1 / 64), 256, 0, stream>>>(x, W1, h1, h1h, NN, F1, IND);
  k_att<H1, D1><<<(NN * H1 + 255) / 256, 256, 0, stream>>>(h1, as1w, ad1w, as1, ad1);
  k_aggs<8, 8, F1, 256, true><<<8 * 256, 256, 0, stream>>>(rowp, csr, h1h, as1, ad1, b1, h2);

  // layer 2
  k_gemm_nt<16><<<dim3((NN + 63) / 64, F2 / 64), 256, 0, stream>>>(h2, W2, hm, hmh, NN, F2, F1);
  k_att<1, F2><<<(NN + 255) / 256, 256, 0, stream>>>(hm, as2w, ad2w, as2, ad2);
  k_aggs<2, 1, F2, 1024, false><<<2 * 1024, 256, 0, stream>>>(rowp, csr, hmh, as2, ad2, b2, out);
}

// Round 4
// 261.863 us; speedup vs baseline: 1.6762x; 1.6762x over previous
//
#include <hip/hip_runtime.h>
#include <hip/hip_fp16.h>

#define NN 50000
#define EE 800000
#define ET (EE + NN)      // edges + self loops = 850000
#define IND 128
#define F1 256            // HEADS*HID
#define H1 8
#define D1 32
#define F2 64
#define NEG 0.2f
#define EPSV 1e-16f

typedef _Float16 half8_t __attribute__((ext_vector_type(8)));
typedef float floatx4 __attribute__((ext_vector_type(4)));

// ---------------- CSR build ----------------
__global__ void k_hist(const int* __restrict__ ei, int* __restrict__ deg) {
  int e = blockIdx.x * blockDim.x + threadIdx.x;
  if (e >= ET) return;
  int d = (e < EE) ? ei[EE + e] : (e - EE);
  atomicAdd(&deg[d], 1);
}

__global__ void k_scan1(const int* __restrict__ deg, int* __restrict__ incl,
                        int* __restrict__ blks) {
  __shared__ int sm[256];
  int t = threadIdx.x;
  int i = blockIdx.x * 256 + t;
  int v = (i < NN) ? deg[i] : 0;
  sm[t] = v;
  __syncthreads();
  for (int off = 1; off < 256; off <<= 1) {
    int add = (t >= off) ? sm[t - off] : 0;
    __syncthreads();
    sm[t] += add;
    __syncthreads();
  }
  if (i < NN) incl[i] = sm[t];
  if (t == 255) blks[blockIdx.x] = sm[t];
}

__global__ void k_scan2(int* __restrict__ blks, int nb) {
  __shared__ int sm[256];
  int t = threadIdx.x;
  sm[t] = (t < nb) ? blks[t] : 0;
  __syncthreads();
  for (int off = 1; off < 256; off <<= 1) {
    int add = (t >= off) ? sm[t - off] : 0;
    __syncthreads();
    sm[t] += add;
    __syncthreads();
  }
  if (t < nb) blks[t] = sm[t];
}

__global__ void k_scan3(const int* __restrict__ deg, const int* __restrict__ blks,
                        int* __restrict__ rowp, int* __restrict__ cursor) {
  int b = blockIdx.x;
  int i = b * 256 + threadIdx.x;
  if (i == 0) rowp[NN] = ET;
  if (i >= NN) return;
  int base = (b > 0) ? blks[b - 1] : 0;
  int excl = rowp[i] - deg[i] + base;
  rowp[i] = excl;
  cursor[i] = excl;
}

__global__ void k_scatter(const int* __restrict__ ei, int* __restrict__ cursor,
                          int* __restrict__ csr) {
  int e = blockIdx.x * blockDim.x + threadIdx.x;
  if (e >= ET) return;
  int s, d;
  if (e < EE) { s = ei[e]; d = ei[EE + e]; }
  else        { s = e - EE; d = s; }
  int pos = atomicAdd(&cursor[d], 1);
  csr[pos] = s;
}

// ---------------- fp32 -> fp16 convert (n4 = n/4) ----------------
__global__ void k_cvt(const float* __restrict__ in, __half* __restrict__ o, int n4) {
  int i = blockIdx.x * blockDim.x + threadIdx.x;
  if (i >= n4) return;
  float4 v = *(const float4*)(in + (size_t)i * 4);
  __half2 p0 = __floats2half2_rn(v.x, v.y);
  __half2 p1 = __floats2half2_rn(v.z, v.w);
  float2 st;
  *(__half2*)&st.x = p0;
  *(__half2*)&st.y = p1;
  *(float2*)(o + (size_t)i * 4) = st;
}

// ---------------- MFMA GEMM: Ch[M,NCF] = A[M,K] * B[NC,K]^T (fp16 in/out) ---
// Block: 256 thr = 4 waves, 64 rows. grid.y tiles of NCT cols. B tile in LDS.
// A-frag: lane&15 = row, (lane>>4)*8 = k-slot (same permutation on B -> safe).
// C/D: col = lane&15, row = (lane>>4)*4 + reg  [HW-verified mapping].
template<int NCT, int K, int NCF>
__global__ __launch_bounds__(256) void k_gemm_mf(const __half* __restrict__ A,
    const __half* __restrict__ Bh, __half* __restrict__ Ch, int M) {
  __shared__ __half Bs[NCT][K + 8];
  int tid = threadIdx.x;
  const float4* src = (const float4*)(Bh + (size_t)blockIdx.y * NCT * K);
  for (int i = tid; i < NCT * K / 8; i += 256) {
    int row = i / (K / 8), kc = i % (K / 8);
    *(float4*)&Bs[row][kc * 8] = src[i];
  }
  __syncthreads();
  int wv = tid >> 6, lane = tid & 63;
  int m0 = blockIdx.x * 64 + wv * 16;
  int ar = lane & 15, ag = lane >> 4;
  int mrow = m0 + ar;
  if (mrow >= M) mrow = M - 1;
  const half8_t* Arow = (const half8_t*)(A + (size_t)mrow * K + ag * 8);
  floatx4 acc[NCT / 16];
#pragma unroll
  for (int t = 0; t < NCT / 16; ++t) acc[t] = (floatx4){0.f, 0.f, 0.f, 0.f};
#pragma unroll
  for (int k0 = 0; k0 < K; k0 += 32) {
    half8_t af = Arow[k0 / 8];
#pragma unroll
    for (int t = 0; t < NCT / 16; ++t) {
      half8_t bf = *(const half8_t*)&Bs[t * 16 + ar][k0 + ag * 8];
      acc[t] = __builtin_amdgcn_mfma_f32_16x16x32_f16(af, bf, acc[t], 0, 0, 0);
    }
  }
#pragma unroll
  for (int t = 0; t < NCT / 16; ++t) {
    int col = blockIdx.y * NCT + t * 16 + ar;
#pragma unroll
    for (int r = 0; r < 4; ++r) {
      int m = m0 + ag * 4 + r;
      if (m < M) Ch[(size_t)m * NCF + col] = __float2half(acc[t][r]);
    }
  }
}

// ---------------- per-node attention logits (fp16 feat, node-major out) ----
template<int H, int D>
__global__ void k_att_h(const __half* __restrict__ h, const float* __restrict__ atts,
                        const float* __restrict__ attd, float* __restrict__ as_,
                        float* __restrict__ ad_) {
  int idx = blockIdx.x * blockDim.x + threadIdx.x;
  if (idx >= NN * H) return;
  int n = idx / H, hh = idx % H;
  const __half* hp = h + (size_t)n * (H * D) + hh * D;
  float s_ = 0.f, d_ = 0.f;
#pragma unroll
  for (int j = 0; j < D; j += 2) {
    float2 hv = __half22float2(*(const __half2*)(hp + j));
    s_ += hv.x * atts[hh * D + j] + hv.y * atts[hh * D + j + 1];
    d_ += hv.x * attd[hh * D + j] + hv.y * attd[hh * D + j + 1];
  }
  as_[idx] = s_;
  ad_[idx] = d_;
}

// ---------------- layer-1 aggregation: one wave/dest, 4-edge unroll --------
// feat [N][256] fp16; out h2h [N][256] fp16 (relu). Softmax folded into
// final divide. 4 independent 512B row-gathers in flight per wave.
__global__ __launch_bounds__(256) void k_agg1(const int* __restrict__ rowp,
    const int* __restrict__ csr, const __half* __restrict__ feat,
    const float* __restrict__ as_, const float* __restrict__ ad_,
    const float* __restrict__ bias, __half* __restrict__ outh) {
  int wid = threadIdx.x >> 6;
  int lane = threadIdx.x & 63;
  int d = blockIdx.x * 4 + wid;
  if (d >= NN) return;
  int hh = lane >> 3;               // (lane*4)/32
  float adv = ad_[d * 8 + hh];
  float acc[4][4] = {};
  float wsv[4] = {};
  int p0 = rowp[d], p1 = rowp[d + 1];
  int p = p0;
  for (; p + 4 <= p1; p += 4) {
    int s0 = csr[p], s1 = csr[p + 1], s2 = csr[p + 2], s3 = csr[p + 3];
    float t0 = as_[s0 * 8 + hh] + adv;
    float t1 = as_[s1 * 8 + hh] + adv;
    float t2 = as_[s2 * 8 + hh] + adv;
    float t3 = as_[s3 * 8 + hh] + adv;
    float2 r0 = *(const float2*)(feat + (size_t)s0 * 256 + lane * 4);
    float2 r1 = *(const float2*)(feat + (size_t)s1 * 256 + lane * 4);
    float2 r2 = *(const float2*)(feat + (size_t)s2 * 256 + lane * 4);
    float2 r3 = *(const float2*)(feat + (size_t)s3 * 256 + lane * 4);
    t0 = (t0 > 0.f) ? t0 : NEG * t0;
    t1 = (t1 > 0.f) ? t1 : NEG * t1;
    t2 = (t2 > 0.f) ? t2 : NEG * t2;
    t3 = (t3 > 0.f) ? t3 : NEG * t3;
    float w0 = __expf(t0), w1 = __expf(t1), w2 = __expf(t2), w3 = __expf(t3);
    wsv[0] += w0; wsv[1] += w1; wsv[2] += w2; wsv[3] += w3;
    float2 l0 = __half22float2(*(__half2*)&r0.x), m0 = __half22float2(*(__half2*)&r0.y);
    float2 l1 = __half22float2(*(__half2*)&r1.x), m1 = __half22float2(*(__half2*)&r1.y);
    float2 l2 = __half22float2(*(__half2*)&r2.x), m2 = __half22float2(*(__half2*)&r2.y);
    float2 l3 = __half22float2(*(__half2*)&r3.x), m3 = __half22float2(*(__half2*)&r3.y);
    acc[0][0] += w0 * l0.x; acc[0][1] += w0 * l0.y; acc[0][2] += w0 * m0.x; acc[0][3] += w0 * m0.y;
    acc[1][0] += w1 * l1.x; acc[1][1] += w1 * l1.y; acc[1][2] += w1 * m1.x; acc[1][3] += w1 * m1.y;
    acc[2][0] += w2 * l2.x; acc[2][1] += w2 * l2.y; acc[2][2] += w2 * m2.x; acc[2][3] += w2 * m2.y;
    acc[3][0] += w3 * l3.x; acc[3][1] += w3 * l3.y; acc[3][2] += w3 * m3.x; acc[3][3] += w3 * m3.y;
  }
  for (; p < p1; ++p) {
    int s = csr[p];
    float t = as_[s * 8 + hh] + adv;
    t = (t > 0.f) ? t : NEG * t;
    float w = __expf(t);
    wsv[0] += w;
    float2 r = *(const float2*)(feat + (size_t)s * 256 + lane * 4);
    float2 lo = __half22float2(*(__half2*)&r.x), hi = __half22float2(*(__half2*)&r.y);
    acc[0][0] += w * lo.x; acc[0][1] += w * lo.y; acc[0][2] += w * hi.x; acc[0][3] += w * hi.y;
  }
  float ws = wsv[0] + wsv[1] + wsv[2] + wsv[3];
  float inv = 1.f / (ws + EPSV);
  float o[4];
#pragma unroll
  for (int v = 0; v < 4; ++v) {
    o[v] = (acc[0][v] + acc[1][v] + acc[2][v] + acc[3][v]) * inv + bias[lane * 4 + v];
    o[v] = fmaxf(o[v], 0.f);        // relu
  }
  __half2 pa = __floats2half2_rn(o[0], o[1]);
  __half2 pb = __floats2half2_rn(o[2], o[3]);
  float2 st;
  *(__half2*)&st.x = pa;
  *(__half2*)&st.y = pb;
  *(float2*)(outh + (size_t)d * 256 + lane * 4) = st;
}

// ---------------- layer-2 aggregation: 32 lanes/edge, 2 slots -------------
__global__ __launch_bounds__(256) void k_agg2(const int* __restrict__ rowp,
    const int* __restrict__ csr, const __half* __restrict__ feat /*[N][64]*/,
    const float* __restrict__ as_, const float* __restrict__ ad_,
    const float* __restrict__ bias, float* __restrict__ out) {
  int wid = threadIdx.x >> 6;
  int lane = threadIdx.x & 63;
  int d = blockIdx.x * 4 + wid;
  if (d >= NN) return;
  int sub = lane >> 5;              // edge slot 0/1
  int ep = lane & 31;               // dim pair
  float adv = ad_[d];
  float a0 = 0.f, a1 = 0.f, ws = 0.f;
  int p0 = rowp[d], p1 = rowp[d + 1];
#pragma unroll 2
  for (int q = p0 + sub; q < p1; q += 2) {
    int s = csr[q];
    float t = as_[s] + adv;
    t = (t > 0.f) ? t : NEG * t;
    float w = __expf(t);
    ws += w;
    float2 f = __half22float2(*(const __half2*)(feat + (size_t)s * 64 + ep * 2));
    a0 += w * f.x;
    a1 += w * f.y;
  }
  a0 += __shfl_xor(a0, 32);
  a1 += __shfl_xor(a1, 32);
  ws += __shfl_xor(ws, 32);
  if (sub == 0) {
    float inv = 1.f / (ws + EPSV);
    float2 o;
    o.x = a0 * inv + bias[ep * 2];
    o.y = a1 * inv + bias[ep * 2 + 1];
    *(float2*)(out + (size_t)d * 64 + ep * 2) = o;
  }
}

extern "C" void kernel_launch(void* const* d_in, const int* in_sizes, int n_in,
                              void* d_out, int out_size, void* d_ws, size_t ws_size,
                              hipStream_t stream) {
  const float* x    = (const float*)d_in[0];
  const int*   ei   = (const int*)d_in[1];
  const float* W1   = (const float*)d_in[2];
  const float* as1w = (const float*)d_in[3];
  const float* ad1w = (const float*)d_in[4];
  const float* b1   = (const float*)d_in[5];
  const float* W2   = (const float*)d_in[6];
  const float* as2w = (const float*)d_in[7];
  const float* ad2w = (const float*)d_in[8];
  const float* b2   = (const float*)d_in[9];
  float* out = (float*)d_out;

  char* W = (char*)d_ws;
  __half* h1h = (__half*)W; W += (size_t)NN * 256 * 2;   // GEMM1 out / att1+agg1 in
  __half* h2h = (__half*)W; W += (size_t)NN * 256 * 2;   // agg1 out / GEMM2 A
  __half* hmh = (__half*)W; W += (size_t)NN * 64 * 2;    // GEMM2 out / att2+agg2 in
  __half* xh  = (__half*)W; W += (size_t)NN * 128 * 2;
  __half* W1h = (__half*)W; W += 256 * 128 * 2;
  __half* W2h = (__half*)W; W += 64 * 256 * 2;
  float* as1 = (float*)W; W += (size_t)NN * 8 * 4;       // node-major [N][8]
  float* ad1 = (float*)W; W += (size_t)NN * 8 * 4;
  float* as2 = (float*)W; W += (size_t)NN * 4;
  float* ad2 = (float*)W; W += (size_t)NN * 4;
  int* deg    = (int*)W;  W += (size_t)NN * 4;
  int* rowp   = (int*)W;  W += (size_t)(NN + 1) * 4;
  int* cursor = (int*)W;  W += (size_t)NN * 4;
  int* blks   = (int*)W;  W += 256 * 4;
  int* csr    = (int*)W;  W += (size_t)ET * 4;

  hipMemsetAsync(deg, 0, NN * sizeof(int), stream);
  int nbE = (ET + 255) / 256;
  int nbN = (NN + 255) / 256;               // 196
  k_hist<<<nbE, 256, 0, stream>>>(ei, deg);
  k_scan1<<<nbN, 256, 0, stream>>>(deg, rowp, blks);
  k_scan2<<<1, 256, 0, stream>>>(blks, nbN);
  k_scan3<<<nbN, 256, 0, stream>>>(deg, blks, rowp, cursor);
  k_scatter<<<nbE, 256, 0, stream>>>(ei, cursor, csr);

  // fp16 conversions
  k_cvt<<<(NN * 128 / 4 + 255) / 256, 256, 0, stream>>>(x, xh, NN * 128 / 4);
  k_cvt<<<(256 * 128 / 4 + 255) / 256, 256, 0, stream>>>(W1, W1h, 256 * 128 / 4);
  k_cvt<<<(64 * 256 / 4 + 255) / 256, 256, 0, stream>>>(W2, W2h, 64 * 256 / 4);

  int mg = (NN + 63) / 64;                  // 782

  // layer 1
  k_gemm_mf<128, 128, 256><<<dim3(mg, 2), 256, 0, stream>>>(xh, W1h, h1h, NN);
  k_att_h<H1, D1><<<(NN * H1 + 255) / 256, 256, 0, stream>>>(h1h, as1w, ad1w, as1, ad1);
  k_agg1<<<(NN + 3) / 4, 256, 0, stream>>>(rowp, csr, h1h, as1, ad1, b1, h2h);

  // layer 2
  k_gemm_mf<64, 256, 64><<<dim3(mg, 1), 256, 0, stream>>>(h2h, W2h, hmh, NN);
  k_att_h<1, F2><<<(NN + 255) / 256, 256, 0, stream>>>(hmh, as2w, ad2w, as2, ad2);
  k_agg2<<<(NN + 3) / 4, 256, 0, stream>>>(rowp, csr, hmh, as2, ad2, b2, out);
}

// Round 5
// 237.751 us; speedup vs baseline: 1.8462x; 1.1014x over previous
//
#include <hip/hip_runtime.h>
#include <hip/hip_fp16.h>

#define NN 50000
#define EE 800000
#define ET (EE + NN)      // edges + self loops = 850000
#define IND 128
#define F1 256            // HEADS*HID
#define H1 8
#define D1 32
#define F2 64
#define NEG 0.2f
#define EPSV 1e-16f

typedef _Float16 half8_t __attribute__((ext_vector_type(8)));
typedef float floatx4 __attribute__((ext_vector_type(4)));

// ---------------- CSR build ----------------
__global__ void k_hist(const int* __restrict__ ei, int* __restrict__ deg) {
  int e = blockIdx.x * blockDim.x + threadIdx.x;
  if (e >= ET) return;
  int d = (e < EE) ? ei[EE + e] : (e - EE);
  atomicAdd(&deg[d], 1);
}

__global__ void k_scan1(const int* __restrict__ deg, int* __restrict__ incl,
                        int* __restrict__ blks) {
  __shared__ int sm[256];
  int t = threadIdx.x;
  int i = blockIdx.x * 256 + t;
  int v = (i < NN) ? deg[i] : 0;
  sm[t] = v;
  __syncthreads();
  for (int off = 1; off < 256; off <<= 1) {
    int add = (t >= off) ? sm[t - off] : 0;
    __syncthreads();
    sm[t] += add;
    __syncthreads();
  }
  if (i < NN) incl[i] = sm[t];
  if (t == 255) blks[blockIdx.x] = sm[t];
}

__global__ void k_scan2(int* __restrict__ blks, int nb) {
  __shared__ int sm[256];
  int t = threadIdx.x;
  sm[t] = (t < nb) ? blks[t] : 0;
  __syncthreads();
  for (int off = 1; off < 256; off <<= 1) {
    int add = (t >= off) ? sm[t - off] : 0;
    __syncthreads();
    sm[t] += add;
    __syncthreads();
  }
  if (t < nb) blks[t] = sm[t];
}

__global__ void k_scan3(const int* __restrict__ deg, const int* __restrict__ blks,
                        int* __restrict__ rowp, int* __restrict__ cursor) {
  int b = blockIdx.x;
  int i = b * 256 + threadIdx.x;
  if (i == 0) rowp[NN] = ET;
  if (i >= NN) return;
  int base = (b > 0) ? blks[b - 1] : 0;
  int excl = rowp[i] - deg[i] + base;
  rowp[i] = excl;
  cursor[i] = excl;
}

__global__ void k_scatter(const int* __restrict__ ei, int* __restrict__ cursor,
                          int* __restrict__ csr) {
  int e = blockIdx.x * blockDim.x + threadIdx.x;
  if (e >= ET) return;
  int s, d;
  if (e < EE) { s = ei[e]; d = ei[EE + e]; }
  else        { s = e - EE; d = s; }
  int pos = atomicAdd(&cursor[d], 1);
  csr[pos] = s;
}

// ---------------- fused fp32 -> fp16 convert: x | W1 | W2 ----------------
#define XN4 (NN * 128 / 4)
#define W1N4 (256 * 128 / 4)
#define W2N4 (64 * 256 / 4)
__global__ void k_cvt3(const float* __restrict__ x, const float* __restrict__ w1,
                       const float* __restrict__ w2, __half* __restrict__ xh,
                       __half* __restrict__ w1h, __half* __restrict__ w2h) {
  int i = blockIdx.x * blockDim.x + threadIdx.x;
  const float* in;
  __half* o;
  if (i < XN4) { in = x; o = xh; }
  else if (i < XN4 + W1N4) { in = w1; o = w1h; i -= XN4; }
  else if (i < XN4 + W1N4 + W2N4) { in = w2; o = w2h; i -= XN4 + W1N4; }
  else return;
  float4 v = *(const float4*)(in + (size_t)i * 4);
  __half2 p0 = __floats2half2_rn(v.x, v.y);
  __half2 p1 = __floats2half2_rn(v.z, v.w);
  float2 st;
  *(__half2*)&st.x = p0;
  *(__half2*)&st.y = p1;
  *(float2*)(o + (size_t)i * 4) = st;
}

// ---------------- MFMA GEMM: Ch[M,NCF] = A[M,K] * B[NC,K]^T (fp16 in/out) ---
template<int NCT, int K, int NCF>
__global__ __launch_bounds__(256) void k_gemm_mf(const __half* __restrict__ A,
    const __half* __restrict__ Bh, __half* __restrict__ Ch, int M) {
  __shared__ __half Bs[NCT][K + 8];
  int tid = threadIdx.x;
  const float4* src = (const float4*)(Bh + (size_t)blockIdx.y * NCT * K);
  for (int i = tid; i < NCT * K / 8; i += 256) {
    int row = i / (K / 8), kc = i % (K / 8);
    *(float4*)&Bs[row][kc * 8] = src[i];
  }
  __syncthreads();
  int wv = tid >> 6, lane = tid & 63;
  int m0 = blockIdx.x * 64 + wv * 16;
  int ar = lane & 15, ag = lane >> 4;
  int mrow = m0 + ar;
  if (mrow >= M) mrow = M - 1;
  const half8_t* Arow = (const half8_t*)(A + (size_t)mrow * K + ag * 8);
  floatx4 acc[NCT / 16];
#pragma unroll
  for (int t = 0; t < NCT / 16; ++t) acc[t] = (floatx4){0.f, 0.f, 0.f, 0.f};
#pragma unroll
  for (int k0 = 0; k0 < K; k0 += 32) {
    half8_t af = Arow[k0 / 8];
#pragma unroll
    for (int t = 0; t < NCT / 16; ++t) {
      half8_t bf = *(const half8_t*)&Bs[t * 16 + ar][k0 + ag * 8];
      acc[t] = __builtin_amdgcn_mfma_f32_16x16x32_f16(af, bf, acc[t], 0, 0, 0);
    }
  }
#pragma unroll
  for (int t = 0; t < NCT / 16; ++t) {
    int col = blockIdx.y * NCT + t * 16 + ar;
#pragma unroll
    for (int r = 0; r < 4; ++r) {
      int m = m0 + ag * 4 + r;
      if (m < M) Ch[(size_t)m * NCF + col] = __float2half(acc[t][r]);
    }
  }
}

// ---------------- per-node attention logits, coalesced ----------------
// Wave covers 64/(F/8) nodes; each lane one 16B chunk (8 dims).
template<int H, int D>
__global__ void k_att2(const __half* __restrict__ h, const float* __restrict__ atts,
                       const float* __restrict__ attd, float* __restrict__ as_,
                       float* __restrict__ ad_) {
  const int F = H * D;
  const int CPR = F / 8;          // chunks per row
  const int NPW = 64 / CPR;       // nodes per wave
  const int CPH = D / 8;          // chunks per head
  int lane = threadIdx.x & 63;
  int wv = threadIdx.x >> 6;
  int n = blockIdx.x * (4 * NPW) + wv * NPW + lane / CPR;
  if (n >= NN) return;
  int c = lane % CPR;
  int head = c / CPH;
  int within = c % CPH;
  half8_t f = *(const half8_t*)(h + (size_t)n * F + c * 8);
  float s_ = 0.f, d_ = 0.f;
#pragma unroll
  for (int j = 0; j < 8; ++j) {
    float fv = (float)f[j];
    s_ += fv * atts[head * D + within * 8 + j];
    d_ += fv * attd[head * D + within * 8 + j];
  }
#pragma unroll
  for (int m = 1; m < CPH; m <<= 1) {
    s_ += __shfl_xor(s_, m);
    d_ += __shfl_xor(d_, m);
  }
  if (within == 0) {
    as_[n * H + head] = s_;
    ad_[n * H + head] = d_;
  }
}

// ---------------- layer-1 aggregation ----------------
// Wave per dest. Macro-iter = 8 edges. Weight phase: lane = (slot 0..7, head
// 0..7) computes ONE (edge,head) weight. Dim phase: 2 edges x 32 lanes x 16B,
// weights/srcs redistributed via ds_bpermute. fp32 accum. Softmax folded
// into the final divide.
__global__ __launch_bounds__(256) void k_agg1(const int* __restrict__ rowp,
    const int* __restrict__ csr, const __half* __restrict__ feat,
    const float* __restrict__ as_, const float* __restrict__ ad_,
    const float* __restrict__ bias, __half* __restrict__ outh) {
  int wid = threadIdx.x >> 6;
  int lane = threadIdx.x & 63;
  int d = blockIdx.x * 4 + wid;
  if (d >= NN) return;
  const int b = lane >> 5;        // edge parity (dim phase)
  const int q = lane & 31;        // 16B chunk within row
  const int h = q >> 2;           // head of this chunk
  const int sw = lane >> 3;       // weight-phase slot
  const int hw = lane & 7;        // weight-phase head
  const char* fb = (const char*)feat;
  float adw = ad_[d * 8 + hw];
  float acc[8] = {};
  float wsacc = 0.f;
  int p0 = rowp[d], p1 = rowp[d + 1];
  int nfull = (p1 - p0) >> 3;
  int p = p0;
  for (int it = 0; it < nfull; ++it, p += 8) {
    int sW = csr[p + sw];
    float t = as_[sW * 8 + hw] + adw;
    t = (t > 0.f) ? t : NEG * t;
    float w = __expf(t);
    wsacc += w;
    int wbits = __float_as_int(w);
#pragma unroll
    for (int i = 0; i < 4; ++i) {
      int slot = 2 * i + b;
      int se = __builtin_amdgcn_ds_bpermute(slot * 32, sW);
      float wv = __int_as_float(
          __builtin_amdgcn_ds_bpermute((slot * 8 + h) * 4, wbits));
      half8_t f = *(const half8_t*)(fb + ((se << 9) | (q << 4)));
#pragma unroll
      for (int j = 0; j < 8; ++j) acc[j] = fmaf(wv, (float)f[j], acc[j]);
    }
  }
  if (p < p1) {                   // masked tail macro-iter
    int pw = p + sw;
    bool v = pw < p1;
    int sW = csr[v ? pw : (p1 - 1)];
    float t = as_[sW * 8 + hw] + adw;
    t = (t > 0.f) ? t : NEG * t;
    float w = v ? __expf(t) : 0.f;
    wsacc += w;
    int wbits = __float_as_int(w);
#pragma unroll
    for (int i = 0; i < 4; ++i) {
      int slot = 2 * i + b;
      int se = __builtin_amdgcn_ds_bpermute(slot * 32, sW);
      float wv = __int_as_float(
          __builtin_amdgcn_ds_bpermute((slot * 8 + h) * 4, wbits));
      half8_t f = *(const half8_t*)(fb + ((se << 9) | (q << 4)));
#pragma unroll
      for (int j = 0; j < 8; ++j) acc[j] = fmaf(wv, (float)f[j], acc[j]);
    }
  }
  // ws: reduce over slots (lane bits 3,4,5) -> lane L holds total for head L&7
  wsacc += __shfl_xor(wsacc, 8);
  wsacc += __shfl_xor(wsacc, 16);
  wsacc += __shfl_xor(wsacc, 32);
  float wst = __int_as_float(
      __builtin_amdgcn_ds_bpermute(h * 4, __float_as_int(wsacc)));
  // acc: combine the two edge-parity halves
#pragma unroll
  for (int j = 0; j < 8; ++j) acc[j] += __shfl_xor(acc[j], 32);
  if (b == 0) {
    float inv = 1.f / (wst + EPSV);
    __half2 packs[4];
#pragma unroll
    for (int j = 0; j < 8; j += 2) {
      float o0 = fmaxf(fmaf(acc[j], inv, 0.f) + bias[q * 8 + j], 0.f);
      float o1 = fmaxf(fmaf(acc[j + 1], inv, 0.f) + bias[q * 8 + j + 1], 0.f);
      packs[j >> 1] = __floats2half2_rn(o0, o1);
    }
    *(float4*)(outh + (size_t)d * 256 + q * 8) = *(float4*)packs;
  }
}

// ---------------- layer-2 aggregation: 8 edges/iter x 8 lanes x 16B --------
__global__ __launch_bounds__(256) void k_agg2(const int* __restrict__ rowp,
    const int* __restrict__ csr, const __half* __restrict__ feat /*[N][64]*/,
    const float* __restrict__ as_, const float* __restrict__ ad_,
    const float* __restrict__ bias, float* __restrict__ out) {
  int wid = threadIdx.x >> 6;
  int lane = threadIdx.x & 63;
  int d = blockIdx.x * 4 + wid;
  if (d >= NN) return;
  const int b = lane >> 3;        // edge slot 0..7
  const int q = lane & 7;         // 16B chunk
  const char* fb = (const char*)feat;
  float adv = ad_[d];
  float acc[8] = {};
  float ws = 0.f;
  int p0 = rowp[d], p1 = rowp[d + 1];
  int nfull = (p1 - p0) >> 3;
  int p = p0;
  for (int it = 0; it < nfull; ++it, p += 8) {
    int se = csr[p + b];
    float t = as_[se] + adv;
    t = (t > 0.f) ? t : NEG * t;
    float w = __expf(t);
    ws += w;
    half8_t f = *(const half8_t*)(fb + ((se << 7) | (q << 4)));
#pragma unroll
    for (int j = 0; j < 8; ++j) acc[j] = fmaf(w, (float)f[j], acc[j]);
  }
  if (p < p1) {
    int pe = p + b;
    bool v = pe < p1;
    int se = csr[v ? pe : (p1 - 1)];
    float t = as_[se] + adv;
    t = (t > 0.f) ? t : NEG * t;
    float w = v ? __expf(t) : 0.f;
    ws += w;
    half8_t f = *(const half8_t*)(fb + ((se << 7) | (q << 4)));
#pragma unroll
    for (int j = 0; j < 8; ++j) acc[j] = fmaf(w, (float)f[j], acc[j]);
  }
  ws += __shfl_xor(ws, 8);
  ws += __shfl_xor(ws, 16);
  ws += __shfl_xor(ws, 32);
#pragma unroll
  for (int j = 0; j < 8; ++j) {
    acc[j] += __shfl_xor(acc[j], 8);
    acc[j] += __shfl_xor(acc[j], 16);
    acc[j] += __shfl_xor(acc[j], 32);
  }
  if (b == 0) {
    float inv = 1.f / (ws + EPSV);
    float o[8];
#pragma unroll
    for (int j = 0; j < 8; ++j) o[j] = acc[j] * inv + bias[q * 8 + j];
    *(float4*)(out + (size_t)d * 64 + q * 8) = *(float4*)&o[0];
    *(float4*)(out + (size_t)d * 64 + q * 8 + 4) = *(float4*)&o[4];
  }
}

extern "C" void kernel_launch(void* const* d_in, const int* in_sizes, int n_in,
                              void* d_out, int out_size, void* d_ws, size_t ws_size,
                              hipStream_t stream) {
  const float* x    = (const float*)d_in[0];
  const int*   ei   = (const int*)d_in[1];
  const float* W1   = (const float*)d_in[2];
  const float* as1w = (const float*)d_in[3];
  const float* ad1w = (const float*)d_in[4];
  const float* b1   = (const float*)d_in[5];
  const float* W2   = (const float*)d_in[6];
  const float* as2w = (const float*)d_in[7];
  const float* ad2w = (const float*)d_in[8];
  const float* b2   = (const float*)d_in[9];
  float* out = (float*)d_out;

  char* W = (char*)d_ws;
  __half* h1h = (__half*)W; W += (size_t)NN * 256 * 2;   // GEMM1 out / att1+agg1 in
  __half* h2h = (__half*)W; W += (size_t)NN * 256 * 2;   // agg1 out / GEMM2 A
  __half* hmh = (__half*)W; W += (size_t)NN * 64 * 2;    // GEMM2 out / att2+agg2 in
  __half* xh  = (__half*)W; W += (size_t)NN * 128 * 2;
  __half* W1h = (__half*)W; W += 256 * 128 * 2;
  __half* W2h = (__half*)W; W += 64 * 256 * 2;
  float* as1 = (float*)W; W += (size_t)NN * 8 * 4;       // node-major [N][8]
  float* ad1 = (float*)W; W += (size_t)NN * 8 * 4;
  float* as2 = (float*)W; W += (size_t)NN * 4;
  float* ad2 = (float*)W; W += (size_t)NN * 4;
  int* deg    = (int*)W;  W += (size_t)NN * 4;
  int* rowp   = (int*)W;  W += (size_t)(NN + 1) * 4;
  int* cursor = (int*)W;  W += (size_t)NN * 4;
  int* blks   = (int*)W;  W += 256 * 4;
  int* csr    = (int*)W;  W += (size_t)ET * 4;

  hipMemsetAsync(deg, 0, NN * sizeof(int), stream);
  int nbE = (ET + 255) / 256;
  int nbN = (NN + 255) / 256;               // 196
  k_hist<<<nbE, 256, 0, stream>>>(ei, deg);
  k_scan1<<<nbN, 256, 0, stream>>>(deg, rowp, blks);
  k_scan2<<<1, 256, 0, stream>>>(blks, nbN);
  k_scan3<<<nbN, 256, 0, stream>>>(deg, blks, rowp, cursor);
  k_scatter<<<nbE, 256, 0, stream>>>(ei, cursor, csr);

  int cvtn = XN4 + W1N4 + W2N4;
  k_cvt3<<<(cvtn + 255) / 256, 256, 0, stream>>>(x, W1, W2, xh, W1h, W2h);

  int mg = (NN + 63) / 64;                  // 782

  // layer 1
  k_gemm_mf<128, 128, 256><<<dim3(mg, 2), 256, 0, stream>>>(xh, W1h, h1h, NN);
  k_att2<H1, D1><<<(NN + 7) / 8, 256, 0, stream>>>(h1h, as1w, ad1w, as1, ad1);
  k_agg1<<<(NN + 3) / 4, 256, 0, stream>>>(rowp, csr, h1h, as1, ad1, b1, h2h);

  // layer 2
  k_gemm_mf<64, 256, 64><<<dim3(mg, 1), 256, 0, stream>>>(h2h, W2h, hmh, NN);
  k_att2<1, F2><<<(NN + 31) / 32, 256, 0, stream>>>(hmh, as2w, ad2w, as2, ad2);
  k_agg2<<<(NN + 3) / 4, 256, 0, stream>>>(rowp, csr, hmh, as2, ad2, b2, out);
}